// Round 8
// baseline (179.342 us; speedup 1.0000x reference)
//
#include <hip/hip_runtime.h>
#include <stdint.h>

// ColBERT MaxSim on MI355X (gfx950), round 14.
// scores[b,c] = sum_n max_s dot(qs[b,n,:], ps[c,s,:])
// qs: (64, 32, 128) f32, ps: (64, 1024, 128) f32, out: (64, 64) f32.
//
// R13 post-mortem: 64-token tiles were NEUTRAL (111.7 vs 111.5) -> with
// gaps constant at 22.4 us (exact in R10), maxsim ~= 38 us in BOTH R11 and
// R13 -> barrier drain was not the governor. maxsim has been invisible
// (below the 43 us unconditional fill wall) for 3 rounds: optimizing blind.
//
// R14: fuse cvt into maxsim via a PER-DOC spin barrier (no grid sync
// needed): the 8 blocks of doc c each convert a disjoint 128-token slice
// of P_c f32->bf16 into static g_psb, rendezvous on a device-scope
// monotonic counter (graph-replay safe: target=(my&~7)+8, no reset), then
// run R13's main loop unchanged (gload_lds staging -- the only proven
// qf-resident path). Q converts f32->reg in the prologue (prologue-only
// transients; R12's demotion came from IN-LOOP staging transients).
// Safety: 512 blocks <= 2/CU min capacity (32 KB LDS, ~120 VGPR) -> all
// resident, no deadlock; stale-line hazard is value-identical (inputs
// constant per iteration).
// Predict: fused kernel VISIBLE in top-5 (~46-52 us) with full counters
// (the real payoff: VGPR/MfmaUtil/Occ of the hot loop); dur 111.7 ->
// ~104-108. Revert to R13 if dur > 115 or any hang.
//
// Budget: fill 43 (unconditional, untouchable) + fused ~46 + gaps ~20.

typedef __bf16 bf16x8 __attribute__((ext_vector_type(8)));
typedef float floatx16 __attribute__((ext_vector_type(16)));

#define QS_N (64u * 32u * 128u)    // 262144
#define PS_N (64u * 1024u * 128u)  // 8388608

// Static bf16 copy of ps (16 MiB .bss) + per-doc arrival counters.
__device__ ushort g_psb[PS_N];
__device__ unsigned g_cnt[64];

__device__ inline bf16x8 cvt8(const float4& a, const float4& b) {
  bf16x8 r;
  r[0] = (__bf16)a.x; r[1] = (__bf16)a.y; r[2] = (__bf16)a.z; r[3] = (__bf16)a.w;
  r[4] = (__bf16)b.x; r[5] = (__bf16)b.y; r[6] = (__bf16)b.z; r[7] = (__bf16)b.w;
  return r;
}

__device__ inline float rmax16(const floatx16& a) {
  // Nested fmaxf triples fuse to v_max3_f32.
  float m0 = fmaxf(fmaxf(a[0], a[1]), fmaxf(a[2], a[3]));
  float m1 = fmaxf(fmaxf(a[4], a[5]), fmaxf(a[6], a[7]));
  float m2 = fmaxf(fmaxf(a[8], a[9]), fmaxf(a[10], a[11]));
  float m3 = fmaxf(fmaxf(a[12], a[13]), fmaxf(a[14], a[15]));
  return fmaxf(fmaxf(m0, m1), fmaxf(m2, m3));
}

// global_load_lds: builtin takes AS1/AS3 pointers; C-style casts addrspacecast.
typedef __attribute__((address_space(1))) const void gas_t;
typedef __attribute__((address_space(3))) void las_t;
__device__ inline void gload_lds16(const ushort* g, ushort* l) {
  __builtin_amdgcn_global_load_lds((gas_t*)g, (las_t*)l, 16, 0, 0);
}

#define ZERO16 {0, 0, 0, 0, 0, 0, 0, 0, 0, 0, 0, 0, 0, 0, 0, 0}

__global__ __launch_bounds__(256) void maxsim_fused(const float* __restrict__ qs,
                                                    const float* __restrict__ ps,
                                                    float* __restrict__ out) {
  const int lane = threadIdx.x & 63;
  const int wave = threadIdx.x >> 6;

  // XCD swizzle: the 8 blocks of doc c land on one XCD -> P_c L2-resident.
  const int xcd = blockIdx.x & 7;
  const int slot = blockIdx.x >> 3;   // 0..63
  const int c = xcd * 8 + (slot >> 3);
  const int bg = slot & 7;
  const int qb0 = bg * 8 + wave * 2;  // this wave's first query (of 2)

  const int row = lane & 31;          // A-frag: s-row; B-frag: query token n
  const int hi8 = (lane >> 5) * 8;    // K-half selector (elements)

  // ---- Phase 1: convert my 128-token slice of P_c (f32 -> bf16). ----
  // Block (c,bg) owns tokens [bg*128, bg*128+128): 4096 float4s, coalesced.
  {
    const int base4 = c * 32768 + bg * 4096;  // float4 index into ps
    const float4* src = (const float4*)ps + base4;
    ushort4* dst = (ushort4*)g_psb + base4;
#pragma unroll
    for (int i = 0; i < 16; ++i) {
      const int idx = threadIdx.x + i * 256;  // 0..4095
      float4 f = src[idx];
      union { ushort4 s; struct { __bf16 a, b, c, d; } h; } o;
      o.h.a = (__bf16)f.x; o.h.b = (__bf16)f.y;
      o.h.c = (__bf16)f.z; o.h.d = (__bf16)f.w;
      dst[idx] = o.s;
    }
  }

  // ---- Phase 2: Q f32 -> qf regs (prologue-only cvt transients). ----
  // qf[bb][k] = Q[qb0+bb][n=row][k*16 + hi8 + 0..7] as bf16 (64 VGPRs).
  bf16x8 qf[2][8];
#pragma unroll
  for (int bb = 0; bb < 2; ++bb) {
    const float* q = qs + ((qb0 + bb) * 32 + row) * 128 + hi8;
#pragma unroll
    for (int k = 0; k < 8; ++k) {
      float4 a = *(const float4*)(q + k * 16);
      float4 b = *(const float4*)(q + k * 16 + 4);
      qf[bb][k] = cvt8(a, b);
    }
  }

  // ---- Phase 3: per-doc rendezvous (8 blocks of doc c). ----
  __threadfence();   // release: P writes visible device-wide
  __syncthreads();   // all threads in block done converting
  if (threadIdx.x == 0) {
    unsigned my = atomicAdd(&g_cnt[c], 1u);        // device-scope (m20)
    unsigned target = (my & ~7u) + 8u;             // end of this iteration's 8
    while (atomicAdd(&g_cnt[c], 0u) < target)
      __builtin_amdgcn_s_sleep(4);
    __threadfence();  // acquire
  }
  __syncthreads();

  // ---- Phase 4: R13 main loop, unchanged (gload_lds from g_psb). ----
  const ushort* psb = g_psb;

  // P tile double-buffer, 64 tokens/tile = 16 KiB each, A-frag order:
  // sub-tile u (32 rows) at u*8192 B, chunk j (=k) at j*1024 B, lane at 16 B.
  __shared__ __align__(16) ushort lds_p[2][8192];

  const int pg_lane = (c * 1024 + row) * 128 + hi8;

  // Prologue: stage tile 0 (wave w issues global chunks m = 4w..4w+3).
#pragma unroll
  for (int jj = 0; jj < 4; ++jj) {
    const int m = wave * 4 + jj;
    const int u = m >> 3, j = m & 7;
    gload_lds16(psb + pg_lane + u * 32 * 128 + j * 16,
                &lds_p[0][u * 4096 + j * 512]);
  }
  __syncthreads();

  float vmax0 = -3.4e38f, vmax1 = -3.4e38f;
  int cb = 0;

#pragma unroll 1
  for (int t = 0; t < 16; ++t) {
    // Stage tile t+1; ~500 cyc latency hides under this tile's 32 MFMAs.
    if (t < 15) {
      const int soff = (t + 1) * 64 * 128;
#pragma unroll
      for (int jj = 0; jj < 4; ++jj) {
        const int m = wave * 4 + jj;
        const int u = m >> 3, j = m & 7;
        gload_lds16(psb + pg_lane + soff + u * 32 * 128 + j * 16,
                    &lds_p[cb ^ 1][u * 4096 + j * 512]);
      }
    }
    // Compute tile t: two 32-row sub-tiles, same 2 acc chains reused.
    const ushort* lp = &lds_p[cb][0] + lane * 8;
#pragma unroll
    for (int u = 0; u < 2; ++u) {
      floatx16 acc0 = ZERO16, acc1 = ZERO16;
#pragma unroll
      for (int k = 0; k < 8; ++k) {
        bf16x8 af = *(const bf16x8*)(lp + u * 4096 + k * 512);
        acc0 = __builtin_amdgcn_mfma_f32_32x32x16_bf16(af, qf[0][k], acc0, 0, 0, 0);
        acc1 = __builtin_amdgcn_mfma_f32_32x32x16_bf16(af, qf[1][k], acc1, 0, 0, 0);
      }
      vmax0 = fmaxf(vmax0, rmax16(acc0));
      vmax1 = fmaxf(vmax1, rmax16(acc1));
    }
    // Barrier: staging of t+1 landed AND all readers of cb are done.
    __syncthreads();
    cb ^= 1;
  }

  // acc D-layout: col = lane&31 = token n; lanes l, l^32 hold complementary
  // row-halves -> max-merge, then butterfly-sum the 32 tokens.
  vmax0 = fmaxf(vmax0, __shfl_xor(vmax0, 32, 64));
  vmax1 = fmaxf(vmax1, __shfl_xor(vmax1, 32, 64));
#pragma unroll
  for (int o = 16; o > 0; o >>= 1) {
    vmax0 += __shfl_xor(vmax0, o, 64);
    vmax1 += __shfl_xor(vmax1, o, 64);
  }
  if (lane == 0) {
    out[(qb0 + 0) * 64 + c] = vmax0;
    out[(qb0 + 1) * 64 + c] = vmax1;
  }
}

extern "C" void kernel_launch(void* const* d_in, const int* in_sizes, int n_in,
                              void* d_out, int out_size, void* d_ws, size_t ws_size,
                              hipStream_t stream) {
  const float* qs = (const float*)d_in[0];
  const float* ps = (const float*)d_in[1];
  float* out = (float*)d_out;
  (void)d_ws; (void)ws_size;  // ws poison fill is unconditional; ws gives us nothing

  maxsim_fused<<<dim3(512), dim3(256), 0, stream>>>(qs, ps, out);
}

// Round 9
// 110.959 us; speedup vs baseline: 1.6163x; 1.6163x over previous
//
#include <hip/hip_runtime.h>
#include <stdint.h>

// ColBERT MaxSim on MI355X (gfx950), round 15.
// scores[b,c] = sum_n max_s dot(qs[b,n,:], ps[c,s,:])
// qs: (64, 32, 128) f32, ps: (64, 1024, 128) f32, out: (64, 64) f32.
//
// R14 post-mortem: in-kernel producer-consumer (per-doc spin rendezvous)
// was a disaster (fused 122 us, MfmaUtil 10.6%): blocks spin on the slowest
// sibling while holding residency, and g_psb round-trips through HBM.
// Reverted. Two-dispatch cvt+maxsim with gload_lds staging stands.
//
// Budget model (all rounds reconciled): dur = fill 43 (unconditional
// harness poison, untouchable) + cvt 8 + maxsim ~38 + gaps ~15-22.
// maxsim wall = 1.05M MFMA x 32 cyc / (1024 SIMD pipes x 2.4GHz) = 13.7 us.
// R13 disproved barrier-drain as the governor (halving barriers: neutral).
//
// R15 theory: DEPENDENT-MFMA LATENCY. Inner loop has only 2 independent
// acc chains; same-chain MFMAs are spaced 2x32=64 issue-cyc. If the
// dependent accumulate latency of v_mfma_f32_32x32x16 exceeds 64 cyc, the
// matrix pipe idles, and at 2 waves/SIMD (grid-limited) nothing fills the
// bubble. Consistent with R10 (2-live-chain structure, MfmaUtil 29%).
// Fix (one variable on R13): unroll the u-subtile loop, interleave 4
// independent chains (u0q0,u0q1,u1q0,u1q1) -> same-chain spacing 128 cyc.
// Regs: qf 64 + acc 64 + af/misc ~32 = ~160 <= 170 (3-waves/EU budget; the
// R7-R9 demotions fired at demand >= 236). Occupancy is grid-limited
// (8 waves/CU) so the register budget costs nothing.
// Readout via dur arithmetic (maxsim stays under the 43 us fill wall):
// win = dur ~95-102; neutral ~111 (theory dead -> s-split next);
// >115 = demotion -> revert R13.

typedef __bf16 bf16x8 __attribute__((ext_vector_type(8)));
typedef float floatx16 __attribute__((ext_vector_type(16)));

#define QS_N (64u * 32u * 128u)    // 262144
#define PS_N (64u * 1024u * 128u)  // 8388608

// Static bf16 staging buffer: qs in [0, QS_N), ps in [QS_N, QS_N+PS_N).
__device__ ushort g_bf[QS_N + PS_N];

__global__ __launch_bounds__(256) void cvt_kernel(const float* __restrict__ qs,
                                                  const float* __restrict__ ps) {
  const int nq4 = QS_N / 4;
  const int n4 = (QS_N + PS_N) / 4;
  int i = blockIdx.x * 256 + threadIdx.x;
  if (i >= n4) return;
  float4 f = (i < nq4) ? ((const float4*)qs)[i] : ((const float4*)ps)[i - nq4];
  union { ushort4 s; struct { __bf16 a, b, c, d; } h; } o;
  o.h.a = (__bf16)f.x; o.h.b = (__bf16)f.y; o.h.c = (__bf16)f.z; o.h.d = (__bf16)f.w;
  ((ushort4*)g_bf)[i] = o.s;
}

__device__ inline float rmax16(const floatx16& a) {
  // Nested fmaxf triples fuse to v_max3_f32.
  float m0 = fmaxf(fmaxf(a[0], a[1]), fmaxf(a[2], a[3]));
  float m1 = fmaxf(fmaxf(a[4], a[5]), fmaxf(a[6], a[7]));
  float m2 = fmaxf(fmaxf(a[8], a[9]), fmaxf(a[10], a[11]));
  float m3 = fmaxf(fmaxf(a[12], a[13]), fmaxf(a[14], a[15]));
  return fmaxf(fmaxf(m0, m1), fmaxf(m2, m3));
}

// global_load_lds: builtin takes AS1/AS3 pointers; C-style casts addrspacecast.
typedef __attribute__((address_space(1))) const void gas_t;
typedef __attribute__((address_space(3))) void las_t;
__device__ inline void gload_lds16(const ushort* g, ushort* l) {
  __builtin_amdgcn_global_load_lds((gas_t*)g, (las_t*)l, 16, 0, 0);
}

#define ZERO16 {0, 0, 0, 0, 0, 0, 0, 0, 0, 0, 0, 0, 0, 0, 0, 0}

__global__ __launch_bounds__(256) void maxsim_kernel(float* __restrict__ out) {
  const ushort* qsb = g_bf;
  const ushort* psb = g_bf + QS_N;

  const int lane = threadIdx.x & 63;
  const int wave = threadIdx.x >> 6;

  // XCD swizzle: the 8 blocks of doc c all land on XCD c>>3 -> P_c (256 KB
  // bf16) L2-resident after the first reader (per-XCD set: 8 docs = 2 MB).
  const int xcd = blockIdx.x & 7;
  const int slot = blockIdx.x >> 3;   // 0..63
  const int c = xcd * 8 + (slot >> 3);
  const int bg = slot & 7;
  const int qb0 = bg * 8 + wave * 2;  // this wave's first query (of 2)

  const int row = lane & 31;          // A-frag: s-row; B-frag: query token n
  const int hi8 = (lane >> 5) * 8;    // K-half selector (elements)

  // Q B-frags straight global->reg (L2/L3-hot, 16B loads), resident all
  // kernel (64 VGPRs): qf[bb][k] = Q[qb0+bb][n=row][k*16 + hi8 + 0..7].
  bf16x8 qf[2][8];
#pragma unroll
  for (int bb = 0; bb < 2; ++bb) {
    const ushort* q = qsb + ((qb0 + bb) * 32 + row) * 128 + hi8;
#pragma unroll
    for (int k = 0; k < 8; ++k)
      qf[bb][k] = *(const bf16x8*)(q + k * 16);
  }

  // P tile double-buffer, 64 tokens/tile = 16 KiB each, A-frag order:
  // sub-tile u (32 rows) at u*8192 B, chunk j (=k) at j*1024 B, lane at 16 B.
  __shared__ __align__(16) ushort lds_p[2][8192];

  // Per-lane global element offset (add s-offset*128 + j*16 per chunk).
  const int pg_lane = (c * 1024 + row) * 128 + hi8;

  // Prologue: stage tile 0 (wave w issues global chunks m = 4w..4w+3;
  // m -> sub-tile u = m>>3, chunk j = m&7).
#pragma unroll
  for (int jj = 0; jj < 4; ++jj) {
    const int m = wave * 4 + jj;
    const int u = m >> 3, j = m & 7;
    gload_lds16(psb + pg_lane + u * 32 * 128 + j * 16,
                &lds_p[0][u * 4096 + j * 512]);
  }
  __syncthreads();

  float vmax0 = -3.4e38f, vmax1 = -3.4e38f;
  int cb = 0;

#pragma unroll 1
  for (int t = 0; t < 16; ++t) {
    // Stage tile t+1 into the back buffer; the ~500 cyc latency hides under
    // this tile's 64 MFMAs.
    if (t < 15) {
      const int soff = (t + 1) * 64 * 128;
#pragma unroll
      for (int jj = 0; jj < 4; ++jj) {
        const int m = wave * 4 + jj;
        const int u = m >> 3, j = m & 7;
        gload_lds16(psb + pg_lane + soff + u * 32 * 128 + j * 16,
                    &lds_p[cb ^ 1][u * 4096 + j * 512]);
      }
    }
    // Compute tile t: 4 INDEPENDENT acc chains (2 sub-tiles x 2 queries)
    // interleaved per k -> same-chain MFMA spacing 4x32=128 issue-cyc,
    // covering the dependent-accumulate latency (the R15 hypothesis).
    const ushort* lp = &lds_p[cb][0] + lane * 8;
    floatx16 a00 = ZERO16, a01 = ZERO16, a10 = ZERO16, a11 = ZERO16;
#pragma unroll
    for (int k = 0; k < 8; ++k) {
      bf16x8 af0 = *(const bf16x8*)(lp + k * 512);
      bf16x8 af1 = *(const bf16x8*)(lp + 4096 + k * 512);
      a00 = __builtin_amdgcn_mfma_f32_32x32x16_bf16(af0, qf[0][k], a00, 0, 0, 0);
      a01 = __builtin_amdgcn_mfma_f32_32x32x16_bf16(af0, qf[1][k], a01, 0, 0, 0);
      a10 = __builtin_amdgcn_mfma_f32_32x32x16_bf16(af1, qf[0][k], a10, 0, 0, 0);
      a11 = __builtin_amdgcn_mfma_f32_32x32x16_bf16(af1, qf[1][k], a11, 0, 0, 0);
    }
    vmax0 = fmaxf(vmax0, fmaxf(rmax16(a00), rmax16(a10)));
    vmax1 = fmaxf(vmax1, fmaxf(rmax16(a01), rmax16(a11)));
    // Barrier: staging of t+1 landed AND all readers of cb are done.
    __syncthreads();
    cb ^= 1;
  }

  // acc D-layout: col = lane&31 = token n; lanes l, l^32 hold complementary
  // row-halves -> max-merge, then butterfly-sum the 32 tokens.
  vmax0 = fmaxf(vmax0, __shfl_xor(vmax0, 32, 64));
  vmax1 = fmaxf(vmax1, __shfl_xor(vmax1, 32, 64));
#pragma unroll
  for (int o = 16; o > 0; o >>= 1) {
    vmax0 += __shfl_xor(vmax0, o, 64);
    vmax1 += __shfl_xor(vmax1, o, 64);
  }
  if (lane == 0) {
    out[(qb0 + 0) * 64 + c] = vmax0;
    out[(qb0 + 1) * 64 + c] = vmax1;
  }
}

extern "C" void kernel_launch(void* const* d_in, const int* in_sizes, int n_in,
                              void* d_out, int out_size, void* d_ws, size_t ws_size,
                              hipStream_t stream) {
  const float* qs = (const float*)d_in[0];
  const float* ps = (const float*)d_in[1];
  float* out = (float*)d_out;
  (void)d_ws; (void)ws_size;  // ws poison fill is unconditional; ws gives us nothing

  const int n4 = (int)((QS_N + PS_N) / 4);
  cvt_kernel<<<(n4 + 255) / 256, 256, 0, stream>>>(qs, ps);
  maxsim_kernel<<<dim3(512), dim3(256), 0, stream>>>(out);
}